// Round 1
// baseline (655.375 us; speedup 1.0000x reference)
//
#include <hip/hip_runtime.h>

// ---------------------------------------------------------------------------
// MR_GNN: 2x (RGCN + GroupEnhance) + linear head.
// R3 -> R4: replace the latency-bound CSR build (global-atomic histogram +
// 3-kernel scan + random 8B scatter with 9x write amplification, ~120us)
// with a two-level bucket build:
//   A) partition edges into 64-node dst-buckets (LDS histogram, sequential
//      per-bucket append streams),
//   B) one block per bucket: (node,rel) histogram + scan in LDS, rp2 slice
//      written with global offsets, pw scatter confined to a ~10KB
//      L2-resident region.
// All 1M-wide random global atomics are gone; fill-path writes become
// (near-)sequential. Gather/GEMM kernels unchanged.
// ---------------------------------------------------------------------------

// ---- CSR build, pass A1: per-bucket edge counts (bucket = dst >> 6) ----
__global__ __launch_bounds__(256) void bucket_hist(const int* __restrict__ ei,
                                                   int* __restrict__ bcnt, int E) {
    __shared__ int h[1024];
    for (int i = threadIdx.x; i < 1024; i += 256) h[i] = 0;
    __syncthreads();
    int base = blockIdx.x * 4096;
#pragma unroll
    for (int k = 0; k < 16; ++k) {
        int e = base + k * 256 + threadIdx.x;
        if (e < E) atomicAdd(&h[ei[E + e] >> 6], 1);
    }
    __syncthreads();
    for (int i = threadIdx.x; i < 1024; i += 256)
        if (h[i]) atomicAdd(&bcnt[i], h[i]);
}

// ---- pass A-scan: exclusive scan of NB (<=1024) bucket counts ----
__global__ __launch_bounds__(1024) void bucket_scan(const int* __restrict__ bcnt,
                                                    int* __restrict__ bofs,
                                                    int* __restrict__ bcur,
                                                    int NB, int E) {
    __shared__ int lds[1024];
    int tid = threadIdx.x;
    int v = (tid < NB) ? bcnt[tid] : 0;
    lds[tid] = v;
    __syncthreads();
    int acc = v;
    for (int off = 1; off < 1024; off <<= 1) {
        int t = (tid >= off) ? lds[tid - off] : 0;
        __syncthreads();
        acc += t;
        lds[tid] = acc;
        __syncthreads();
    }
    int excl = acc - v;
    if (tid < NB) { bofs[tid] = excl; bcur[tid] = excl; }
    if (tid == 0) bofs[NB] = E;
}

// ---- pass A2: partition edge records into bucket streams ----
// recA[pos] = (src, w_bits); recB[pos] = dst*4 + rel
__global__ void partition(const int* __restrict__ ei, const int* __restrict__ et,
                          const float* __restrict__ ew, int* __restrict__ bcur,
                          int2* __restrict__ recA, int* __restrict__ recB, int E) {
    int e = blockIdx.x * 256 + threadIdx.x;
    if (e >= E) return;
    int dst = ei[E + e];
    int pos = atomicAdd(&bcur[dst >> 6], 1);
    recA[pos] = make_int2(ei[e], __float_as_int(ew[e]));
    recB[pos] = dst * 4 + et[e];
}

// ---- pass B: per-bucket (node,rel) hist + scan in LDS, write rp2 + pw ----
// One block per bucket of 64 nodes (256 (node,rel) counters).
__global__ __launch_bounds__(256) void bucket_fill(
    const int2* __restrict__ recA, const int* __restrict__ recB,
    const int* __restrict__ bofs, int* __restrict__ rp2, int2* __restrict__ pw,
    int N) {
    __shared__ int cnt[256];
    __shared__ int cur[256];
    __shared__ int wsum[4];
    const int b = blockIdx.x;
    const int tid = threadIdx.x;
    const int beg = bofs[b], end = bofs[b + 1];
    const int rebase = b << 8;  // base index in (dst*4+rel) space
    cnt[tid] = 0;
    __syncthreads();
    for (int i = beg + tid; i < end; i += 256)
        atomicAdd(&cnt[recB[i] - rebase], 1);
    __syncthreads();
    // exclusive scan of the 256 counters (4 waves + wave-sum fixup)
    int v = cnt[tid];
    int lane = tid & 63, wid = tid >> 6;
    int ws = v;
#pragma unroll
    for (int off = 1; off < 64; off <<= 1) {
        int t = __shfl_up(ws, off);
        if (lane >= off) ws += t;
    }
    if (lane == 63) wsum[wid] = ws;
    __syncthreads();
    int wb = 0;
    for (int w = 0; w < wid; ++w) wb += wsum[w];
    int excl = wb + ws - v;      // exclusive prefix within bucket
    int gpos = beg + excl;       // global CSR position
    if (rebase + tid <= 4 * N) rp2[rebase + tid] = gpos;
    cur[tid] = excl;
    __syncthreads();
    for (int i = beg + tid; i < end; i += 256) {
        int l = recB[i] - rebase;
        int p = beg + atomicAdd(&cur[l], 1);
        pw[p] = recA[i];  // scatter confined to [beg,end): ~10KB, L2-resident
    }
}

__device__ __forceinline__ float4 quad_reduce(float4 a) {
#pragma unroll
    for (int off = 16; off < 64; off <<= 1) {
        a.x += __shfl_xor(a.x, off);
        a.y += __shfl_xor(a.y, off);
        a.z += __shfl_xor(a.z, off);
        a.w += __shfl_xor(a.w, off);
    }
    return a;
}

// one wave per node; lane = 16*q + m: quarter q handles edges beg+q+4k,
// m indexes a float4 of the 64-feature row. 4 relation segments in sequence.
__global__ __launch_bounds__(256) void gather_rel(
    const float* __restrict__ X, const int* __restrict__ rp2,
    const int2* __restrict__ pw, float* __restrict__ aggR, int N) {
    int node = blockIdx.x * 4 + (threadIdx.x >> 6);
    if (node >= N) return;
    int lane = threadIdx.x & 63;
    int q = lane >> 4, m = lane & 15;
#pragma unroll
    for (int r = 0; r < 4; ++r) {
        int beg = rp2[node * 4 + r], end = rp2[node * 4 + r + 1];
        float4 acc = make_float4(0.f, 0.f, 0.f, 0.f);
        int i = beg + q;
        for (; i + 4 < end; i += 8) {  // two independent gathers per iter
            int2 a = pw[i];
            int2 b = pw[i + 4];
            float4 xa = *reinterpret_cast<const float4*>(X + (size_t)a.x * 64 + m * 4);
            float4 xb = *reinterpret_cast<const float4*>(X + (size_t)b.x * 64 + m * 4);
            float wa = __int_as_float(a.y), wb = __int_as_float(b.y);
            acc.x += wa * xa.x; acc.y += wa * xa.y; acc.z += wa * xa.z; acc.w += wa * xa.w;
            acc.x += wb * xb.x; acc.y += wb * xb.y; acc.z += wb * xb.z; acc.w += wb * xb.w;
        }
        if (i < end) {
            int2 a = pw[i];
            float4 xa = *reinterpret_cast<const float4*>(X + (size_t)a.x * 64 + m * 4);
            float wa = __int_as_float(a.y);
            acc.x += wa * xa.x; acc.y += wa * xa.y; acc.z += wa * xa.z; acc.w += wa * xa.w;
        }
        acc = quad_reduce(acc);
        if (q == r)
            *reinterpret_cast<float4*>(aggR + (size_t)node * 256 + r * 64 + m * 4) = acc;
    }
}

__global__ __launch_bounds__(256) void gather_plain(
    const float* __restrict__ H, const int* __restrict__ rp2,
    const int2* __restrict__ pw, float* __restrict__ agg, int N) {
    int node = blockIdx.x * 4 + (threadIdx.x >> 6);
    if (node >= N) return;
    int lane = threadIdx.x & 63;
    int q = lane >> 4, m = lane & 15;
    int beg = rp2[node * 4], end = rp2[node * 4 + 4];
    float4 acc = make_float4(0.f, 0.f, 0.f, 0.f);
    int i = beg + q;
    for (; i + 4 < end; i += 8) {
        int2 a = pw[i];
        int2 b = pw[i + 4];
        float4 xa = *reinterpret_cast<const float4*>(H + (size_t)a.x * 64 + m * 4);
        float4 xb = *reinterpret_cast<const float4*>(H + (size_t)b.x * 64 + m * 4);
        float wa = __int_as_float(a.y), wb = __int_as_float(b.y);
        acc.x += wa * xa.x; acc.y += wa * xa.y; acc.z += wa * xa.z; acc.w += wa * xa.w;
        acc.x += wb * xb.x; acc.y += wb * xb.y; acc.z += wb * xb.z; acc.w += wb * xb.w;
    }
    if (i < end) {
        int2 a = pw[i];
        float4 xa = *reinterpret_cast<const float4*>(H + (size_t)a.x * 64 + m * 4);
        float wa = __int_as_float(a.y);
        acc.x += wa * xa.x; acc.y += wa * xa.y; acc.z += wa * xa.z; acc.w += wa * xa.w;
    }
    acc = quad_reduce(acc);
    if (q == 0)
        *reinterpret_cast<float4*>(agg + (size_t)node * 64 + m * 4) = acc;
}

// ---------------------------------------------------------------------------
// Node-side tiled GEMM (deg from rp2 row bounds).
// MODE 0 (rgcn):  OUT = relu((X@B0 + AGG@B1) / deg)        OUT: N x 64
// MODE 1 (group): OUT = X + alpha*((AGG@B0)/deg + bias)    OUT: N x 64
// MODE 2 (head):  OUT = X@B0 + bias                        OUT: N x 32
// ---------------------------------------------------------------------------
template <int MODE>
__global__ __launch_bounds__(256) void node_gemm(
    const float* __restrict__ X, const float* __restrict__ AGG,
    const float* __restrict__ B0, const float* __restrict__ B1,
    const float* __restrict__ bias, const float* __restrict__ alphap,
    const int* __restrict__ rp2, float* __restrict__ OUT, int N) {
    __shared__ float As[64][68];
    __shared__ float Bs[64][64];
    const int tid = threadIdx.x;
    const int tx = tid & 15, ty = tid >> 4;
    const int row0 = blockIdx.x * 64;
    float acc[4][4] = {};

    const int nchunks = (MODE == 0) ? 5 : 1;
    for (int c = 0; c < nchunks; ++c) {
        const float* A;
        int lda;
        const float* B;
        int ldb, bcols;
        if (MODE == 0) {
            if (c == 0) { A = X; lda = 64; B = B0; }
            else        { A = AGG + (c - 1) * 64; lda = 256; B = B1 + (size_t)(c - 1) * 64 * 64; }
            ldb = 64; bcols = 64;
        } else if (MODE == 1) {
            A = AGG; lda = 64; B = B0; ldb = 64; bcols = 64;
        } else {
            A = X; lda = 64; B = B0; ldb = 32; bcols = 32;
        }
        if (c) __syncthreads();
#pragma unroll
        for (int q = 0; q < 4; ++q) {
            int f = q * 256 + tid;
            int r = f >> 4;
            int c4 = (f & 15) << 2;
            float4 v = make_float4(0.f, 0.f, 0.f, 0.f);
            int vr = row0 + r;
            if (vr < N) v = *reinterpret_cast<const float4*>(A + (size_t)vr * lda + c4);
            *reinterpret_cast<float4*>(&As[r][c4]) = v;
            float4 bv = make_float4(0.f, 0.f, 0.f, 0.f);
            if (c4 < bcols) bv = *reinterpret_cast<const float4*>(B + (size_t)r * ldb + c4);
            *reinterpret_cast<float4*>(&Bs[r][c4]) = bv;
        }
        __syncthreads();
#pragma unroll 8
        for (int k = 0; k < 64; ++k) {
            float4 b = *reinterpret_cast<const float4*>(&Bs[k][tx * 4]);
            float a0 = As[ty * 4 + 0][k];
            float a1 = As[ty * 4 + 1][k];
            float a2 = As[ty * 4 + 2][k];
            float a3 = As[ty * 4 + 3][k];
            acc[0][0] += a0 * b.x; acc[0][1] += a0 * b.y; acc[0][2] += a0 * b.z; acc[0][3] += a0 * b.w;
            acc[1][0] += a1 * b.x; acc[1][1] += a1 * b.y; acc[1][2] += a1 * b.z; acc[1][3] += a1 * b.w;
            acc[2][0] += a2 * b.x; acc[2][1] += a2 * b.y; acc[2][2] += a2 * b.z; acc[2][3] += a2 * b.w;
            acc[3][0] += a3 * b.x; acc[3][1] += a3 * b.y; acc[3][2] += a3 * b.z; acc[3][3] += a3 * b.w;
        }
    }

    const float alpha = (MODE == 1) ? alphap[0] : 0.f;
#pragma unroll
    for (int i = 0; i < 4; ++i) {
        int vr = row0 + ty * 4 + i;
        if (vr >= N) continue;
        float dg = 1.f;
        if (MODE != 2) dg = fmaxf((float)(rp2[vr * 4 + 4] - rp2[vr * 4]), 1.f);
#pragma unroll
        for (int j = 0; j < 4; ++j) {
            int col = tx * 4 + j;
            if (MODE == 0) {
                OUT[(size_t)vr * 64 + col] = fmaxf(acc[i][j] / dg, 0.f);
            } else if (MODE == 1) {
                OUT[(size_t)vr * 64 + col] =
                    X[(size_t)vr * 64 + col] + alpha * (acc[i][j] / dg + bias[col]);
            } else {
                if (col < 32) OUT[(size_t)vr * 32 + col] = acc[i][j] + bias[col];
            }
        }
    }
}

extern "C" void kernel_launch(void* const* d_in, const int* in_sizes, int n_in,
                              void* d_out, int out_size, void* d_ws, size_t ws_size,
                              hipStream_t stream) {
    const float* x      = (const float*)d_in[0];
    const int*   ei     = (const int*)d_in[1];
    const int*   et     = (const int*)d_in[2];
    const float* ew     = (const float*)d_in[3];
    const float* W1     = (const float*)d_in[4];
    const float* W01    = (const float*)d_in[5];
    const float* alpha1 = (const float*)d_in[6];
    const float* projW1 = (const float*)d_in[7];
    const float* projb1 = (const float*)d_in[8];
    const float* W2     = (const float*)d_in[9];
    const float* W02    = (const float*)d_in[10];
    const float* alpha2 = (const float*)d_in[11];
    const float* projW2 = (const float*)d_in[12];
    const float* projb2 = (const float*)d_in[13];
    const float* outW   = (const float*)d_in[14];
    const float* outb   = (const float*)d_in[15];
    const int N = in_sizes[0] / 64;
    const int E = in_sizes[2];
    const int M = 4 * N;            // (dst, rel) segments
    const int NB = (N + 63) >> 6;   // 64-node dst buckets (NB <= 1024 for N <= 65536)

    // workspace (4-byte units):
    // bcnt[1024] | bofs[1032] | bcur[1024] | rp2[M+1 (+pad to even)] |
    // pw int2[E] | aggR[N*256] (recA int2[E] + recB int[E] aliased inside,
    // CSR-build only) | h[N*64] | g[N*64]
    int*   bcnt = (int*)d_ws;
    int*   bofs = bcnt + 1024;
    int*   bcur = bofs + 1032;
    int*   rp2  = bcur + 1024;
    int2*  pw   = (int2*)(rp2 + ((M + 2) & ~1));
    float* aggR = (float*)(pw + E);
    int2*  recA = (int2*)aggR;            // alias: dead once gather_rel runs
    int*   recB = (int*)(recA + E);
    float* hbuf = aggR + (size_t)N * 256;
    float* gbuf = hbuf + (size_t)N * 64;

    const int gatherBlocks = (N + 3) / 4;
    const int gemmBlocks = (N + 63) / 64;
    const int eBlocks = (E + 255) / 256;

    // ---- CSR build (bucketed, once per call) ----
    hipMemsetAsync(bcnt, 0, 1024 * sizeof(int), stream);
    bucket_hist<<<(E + 4095) / 4096, 256, 0, stream>>>(ei, bcnt, E);
    bucket_scan<<<1, 1024, 0, stream>>>(bcnt, bofs, bcur, NB, E);
    partition<<<eBlocks, 256, 0, stream>>>(ei, et, ew, bcur, recA, recB, E);
    bucket_fill<<<NB, 256, 0, stream>>>(recA, recB, bofs, rp2, pw, N);

    // ---- layer 1 ----
    gather_rel<<<gatherBlocks, 256, 0, stream>>>(x, rp2, pw, aggR, N);
    node_gemm<0><<<gemmBlocks, 256, 0, stream>>>(x, aggR, W01, W1, nullptr, nullptr, rp2, hbuf, N);
    gather_plain<<<gatherBlocks, 256, 0, stream>>>(hbuf, rp2, pw, aggR, N);
    node_gemm<1><<<gemmBlocks, 256, 0, stream>>>(hbuf, aggR, projW1, nullptr, projb1, alpha1, rp2, gbuf, N);

    // ---- layer 2 ----
    gather_rel<<<gatherBlocks, 256, 0, stream>>>(gbuf, rp2, pw, aggR, N);
    node_gemm<0><<<gemmBlocks, 256, 0, stream>>>(gbuf, aggR, W02, W2, nullptr, nullptr, rp2, hbuf, N);
    gather_plain<<<gatherBlocks, 256, 0, stream>>>(hbuf, rp2, pw, aggR, N);
    node_gemm<1><<<gemmBlocks, 256, 0, stream>>>(hbuf, aggR, projW2, nullptr, projb2, alpha2, rp2, gbuf, N);

    // ---- head ----
    node_gemm<2><<<gemmBlocks, 256, 0, stream>>>(gbuf, nullptr, outW, nullptr, outb, nullptr, rp2, (float*)d_out, N);
}

// Round 2
// 497.305 us; speedup vs baseline: 1.3179x; 1.3179x over previous
//
#include <hip/hip_runtime.h>

// ---------------------------------------------------------------------------
// MR_GNN: 2x (RGCN + GroupEnhance) + linear head.
// R4 -> R5: partition pass was contention-bound (1M returning atomics on 782
// global counters, 238us) with 6x write amplification. Replace with a
// block-aggregated radix-partition:
//   - coarse buckets (dst>>8, <=256 per chip run), LDS histogram per block,
//   - ONE global atomicAdd per (block,bucket) to reserve a contiguous run
//     (~12K global atomics total instead of 1M),
//   - pass-2 scatter into reserved runs (~670B contiguous per run -> ~1.15x
//     write amplification instead of ~6x).
// bucket_fill moves to 256-node buckets (1024 (node,rel) LDS counters).
// Gather/GEMM kernels unchanged; CSR layout identical.
// ---------------------------------------------------------------------------

#define PART_EPB 16384  // edges per partition/hist block (256 thr x 64)

// ---- CSR build, pass A1: per-bucket edge counts (bucket = dst >> 8) ----
__global__ __launch_bounds__(256) void bucket_hist(const int* __restrict__ ei,
                                                   int* __restrict__ bcnt,
                                                   int E, int NB) {
    __shared__ int h[1024];
    for (int i = threadIdx.x; i < 1024; i += 256) h[i] = 0;
    __syncthreads();
    int base = blockIdx.x * PART_EPB;
#pragma unroll
    for (int k = 0; k < PART_EPB / 256; ++k) {
        int e = base + k * 256 + threadIdx.x;
        if (e < E) atomicAdd(&h[ei[E + e] >> 8], 1);
    }
    __syncthreads();
    for (int i = threadIdx.x; i < NB; i += 256)
        if (h[i]) atomicAdd(&bcnt[i], h[i]);
}

// ---- pass A-scan: exclusive scan of NB (<=1024) bucket counts ----
__global__ __launch_bounds__(1024) void bucket_scan(const int* __restrict__ bcnt,
                                                    int* __restrict__ bofs,
                                                    int* __restrict__ bcur,
                                                    int NB, int E) {
    __shared__ int lds[1024];
    int tid = threadIdx.x;
    int v = (tid < NB) ? bcnt[tid] : 0;
    lds[tid] = v;
    __syncthreads();
    int acc = v;
    for (int off = 1; off < 1024; off <<= 1) {
        int t = (tid >= off) ? lds[tid - off] : 0;
        __syncthreads();
        acc += t;
        lds[tid] = acc;
        __syncthreads();
    }
    int excl = acc - v;
    if (tid < NB) { bofs[tid] = excl; bcur[tid] = excl; }
    if (tid == 0) bofs[NB] = E;
}

// ---- pass A2: block-aggregated partition into bucket streams ----
// pass 1: LDS bucket histogram over this block's 16K edges;
// reserve: one global atomicAdd per (block,bucket);
// pass 2: scatter into the reserved contiguous runs.
// recA[pos] = (src, w_bits); recB[pos] = dst*4 + rel
__global__ __launch_bounds__(256) void partition(const int* __restrict__ ei,
                                                 const int* __restrict__ et,
                                                 const float* __restrict__ ew,
                                                 int* __restrict__ gcur,
                                                 int2* __restrict__ recA,
                                                 int* __restrict__ recB,
                                                 int E, int NB) {
    __shared__ int hist[1024];
    __shared__ int base[1024];
    const int tid = threadIdx.x;
    const int blockBase = blockIdx.x * PART_EPB;
    for (int i = tid; i < 1024; i += 256) hist[i] = 0;
    __syncthreads();
#pragma unroll
    for (int k = 0; k < PART_EPB / 256; ++k) {
        int e = blockBase + k * 256 + tid;
        if (e < E) atomicAdd(&hist[ei[E + e] >> 8], 1);
    }
    __syncthreads();
    for (int i = tid; i < NB; i += 256) {
        int h = hist[i];
        base[i] = h ? atomicAdd(&gcur[i], h) : 0;
    }
    __syncthreads();
    for (int i = tid; i < 1024; i += 256) hist[i] = 0;  // reuse as run cursor
    __syncthreads();
#pragma unroll
    for (int k = 0; k < PART_EPB / 256; ++k) {
        int e = blockBase + k * 256 + tid;
        if (e >= E) continue;
        int dst = ei[E + e];
        int b = dst >> 8;
        int pos = base[b] + atomicAdd(&hist[b], 1);
        recA[pos] = make_int2(ei[e], __float_as_int(ew[e]));
        recB[pos] = dst * 4 + et[e];
    }
}

// ---- pass B: per-bucket (node,rel) hist + scan in LDS, write rp2 + pw ----
// One block per bucket of 256 nodes (1024 (node,rel) counters, 4/thread).
__global__ __launch_bounds__(256) void bucket_fill(
    const int2* __restrict__ recA, const int* __restrict__ recB,
    const int* __restrict__ bofs, int* __restrict__ rp2, int2* __restrict__ pw,
    int N) {
    __shared__ int cnt[1024];
    __shared__ int cur[1024];
    __shared__ int wsum[4];
    const int b = blockIdx.x;
    const int tid = threadIdx.x;
    const int beg = bofs[b], end = bofs[b + 1];
    const int rebase = b << 10;  // base index in (dst*4+rel) space
    for (int j = 0; j < 4; ++j) cnt[tid * 4 + j] = 0;
    __syncthreads();
    for (int i = beg + tid; i < end; i += 256)
        atomicAdd(&cnt[recB[i] - rebase], 1);
    __syncthreads();
    // exclusive scan of the 1024 counters: 4 consecutive per thread,
    // wave scan of thread sums + wave-sum fixup.
    int v[4];
    int s = 0;
#pragma unroll
    for (int j = 0; j < 4; ++j) { v[j] = cnt[tid * 4 + j]; s += v[j]; }
    int lane = tid & 63, wid = tid >> 6;
    int ws = s;
#pragma unroll
    for (int off = 1; off < 64; off <<= 1) {
        int t = __shfl_up(ws, off);
        if (lane >= off) ws += t;
    }
    if (lane == 63) wsum[wid] = ws;
    __syncthreads();
    int wb = 0;
    for (int w = 0; w < wid; ++w) wb += wsum[w];
    int run = beg + wb + ws - s;  // global CSR position of this thread's 1st counter
#pragma unroll
    for (int j = 0; j < 4; ++j) {
        int idx = rebase + tid * 4 + j;
        if (idx <= 4 * N) rp2[idx] = run;
        cur[tid * 4 + j] = run;  // global write cursor for this (node,rel)
        run += v[j];
    }
    __syncthreads();
    for (int i = beg + tid; i < end; i += 256) {
        int l = recB[i] - rebase;
        int p = atomicAdd(&cur[l], 1);
        pw[p] = recA[i];  // scatter confined to [beg,end): ~40KB, L2-resident
    }
}

__device__ __forceinline__ float4 quad_reduce(float4 a) {
#pragma unroll
    for (int off = 16; off < 64; off <<= 1) {
        a.x += __shfl_xor(a.x, off);
        a.y += __shfl_xor(a.y, off);
        a.z += __shfl_xor(a.z, off);
        a.w += __shfl_xor(a.w, off);
    }
    return a;
}

// one wave per node; lane = 16*q + m: quarter q handles edges beg+q+4k,
// m indexes a float4 of the 64-feature row. 4 relation segments in sequence.
__global__ __launch_bounds__(256) void gather_rel(
    const float* __restrict__ X, const int* __restrict__ rp2,
    const int2* __restrict__ pw, float* __restrict__ aggR, int N) {
    int node = blockIdx.x * 4 + (threadIdx.x >> 6);
    if (node >= N) return;
    int lane = threadIdx.x & 63;
    int q = lane >> 4, m = lane & 15;
#pragma unroll
    for (int r = 0; r < 4; ++r) {
        int beg = rp2[node * 4 + r], end = rp2[node * 4 + r + 1];
        float4 acc = make_float4(0.f, 0.f, 0.f, 0.f);
        int i = beg + q;
        for (; i + 4 < end; i += 8) {  // two independent gathers per iter
            int2 a = pw[i];
            int2 b = pw[i + 4];
            float4 xa = *reinterpret_cast<const float4*>(X + (size_t)a.x * 64 + m * 4);
            float4 xb = *reinterpret_cast<const float4*>(X + (size_t)b.x * 64 + m * 4);
            float wa = __int_as_float(a.y), wb = __int_as_float(b.y);
            acc.x += wa * xa.x; acc.y += wa * xa.y; acc.z += wa * xa.z; acc.w += wa * xa.w;
            acc.x += wb * xb.x; acc.y += wb * xb.y; acc.z += wb * xb.z; acc.w += wb * xb.w;
        }
        if (i < end) {
            int2 a = pw[i];
            float4 xa = *reinterpret_cast<const float4*>(X + (size_t)a.x * 64 + m * 4);
            float wa = __int_as_float(a.y);
            acc.x += wa * xa.x; acc.y += wa * xa.y; acc.z += wa * xa.z; acc.w += wa * xa.w;
        }
        acc = quad_reduce(acc);
        if (q == r)
            *reinterpret_cast<float4*>(aggR + (size_t)node * 256 + r * 64 + m * 4) = acc;
    }
}

__global__ __launch_bounds__(256) void gather_plain(
    const float* __restrict__ H, const int* __restrict__ rp2,
    const int2* __restrict__ pw, float* __restrict__ agg, int N) {
    int node = blockIdx.x * 4 + (threadIdx.x >> 6);
    if (node >= N) return;
    int lane = threadIdx.x & 63;
    int q = lane >> 4, m = lane & 15;
    int beg = rp2[node * 4], end = rp2[node * 4 + 4];
    float4 acc = make_float4(0.f, 0.f, 0.f, 0.f);
    int i = beg + q;
    for (; i + 4 < end; i += 8) {
        int2 a = pw[i];
        int2 b = pw[i + 4];
        float4 xa = *reinterpret_cast<const float4*>(H + (size_t)a.x * 64 + m * 4);
        float4 xb = *reinterpret_cast<const float4*>(H + (size_t)b.x * 64 + m * 4);
        float wa = __int_as_float(a.y), wb = __int_as_float(b.y);
        acc.x += wa * xa.x; acc.y += wa * xa.y; acc.z += wa * xa.z; acc.w += wa * xa.w;
        acc.x += wb * xb.x; acc.y += wb * xb.y; acc.z += wb * xb.z; acc.w += wb * xb.w;
    }
    if (i < end) {
        int2 a = pw[i];
        float4 xa = *reinterpret_cast<const float4*>(H + (size_t)a.x * 64 + m * 4);
        float wa = __int_as_float(a.y);
        acc.x += wa * xa.x; acc.y += wa * xa.y; acc.z += wa * xa.z; acc.w += wa * xa.w;
    }
    acc = quad_reduce(acc);
    if (q == 0)
        *reinterpret_cast<float4*>(agg + (size_t)node * 64 + m * 4) = acc;
}

// ---------------------------------------------------------------------------
// Node-side tiled GEMM (deg from rp2 row bounds).
// MODE 0 (rgcn):  OUT = relu((X@B0 + AGG@B1) / deg)        OUT: N x 64
// MODE 1 (group): OUT = X + alpha*((AGG@B0)/deg + bias)    OUT: N x 64
// MODE 2 (head):  OUT = X@B0 + bias                        OUT: N x 32
// ---------------------------------------------------------------------------
template <int MODE>
__global__ __launch_bounds__(256) void node_gemm(
    const float* __restrict__ X, const float* __restrict__ AGG,
    const float* __restrict__ B0, const float* __restrict__ B1,
    const float* __restrict__ bias, const float* __restrict__ alphap,
    const int* __restrict__ rp2, float* __restrict__ OUT, int N) {
    __shared__ float As[64][68];
    __shared__ float Bs[64][64];
    const int tid = threadIdx.x;
    const int tx = tid & 15, ty = tid >> 4;
    const int row0 = blockIdx.x * 64;
    float acc[4][4] = {};

    const int nchunks = (MODE == 0) ? 5 : 1;
    for (int c = 0; c < nchunks; ++c) {
        const float* A;
        int lda;
        const float* B;
        int ldb, bcols;
        if (MODE == 0) {
            if (c == 0) { A = X; lda = 64; B = B0; }
            else        { A = AGG + (c - 1) * 64; lda = 256; B = B1 + (size_t)(c - 1) * 64 * 64; }
            ldb = 64; bcols = 64;
        } else if (MODE == 1) {
            A = AGG; lda = 64; B = B0; ldb = 64; bcols = 64;
        } else {
            A = X; lda = 64; B = B0; ldb = 32; bcols = 32;
        }
        if (c) __syncthreads();
#pragma unroll
        for (int q = 0; q < 4; ++q) {
            int f = q * 256 + tid;
            int r = f >> 4;
            int c4 = (f & 15) << 2;
            float4 v = make_float4(0.f, 0.f, 0.f, 0.f);
            int vr = row0 + r;
            if (vr < N) v = *reinterpret_cast<const float4*>(A + (size_t)vr * lda + c4);
            *reinterpret_cast<float4*>(&As[r][c4]) = v;
            float4 bv = make_float4(0.f, 0.f, 0.f, 0.f);
            if (c4 < bcols) bv = *reinterpret_cast<const float4*>(B + (size_t)r * ldb + c4);
            *reinterpret_cast<float4*>(&Bs[r][c4]) = bv;
        }
        __syncthreads();
#pragma unroll 8
        for (int k = 0; k < 64; ++k) {
            float4 b = *reinterpret_cast<const float4*>(&Bs[k][tx * 4]);
            float a0 = As[ty * 4 + 0][k];
            float a1 = As[ty * 4 + 1][k];
            float a2 = As[ty * 4 + 2][k];
            float a3 = As[ty * 4 + 3][k];
            acc[0][0] += a0 * b.x; acc[0][1] += a0 * b.y; acc[0][2] += a0 * b.z; acc[0][3] += a0 * b.w;
            acc[1][0] += a1 * b.x; acc[1][1] += a1 * b.y; acc[1][2] += a1 * b.z; acc[1][3] += a1 * b.w;
            acc[2][0] += a2 * b.x; acc[2][1] += a2 * b.y; acc[2][2] += a2 * b.z; acc[2][3] += a2 * b.w;
            acc[3][0] += a3 * b.x; acc[3][1] += a3 * b.y; acc[3][2] += a3 * b.z; acc[3][3] += a3 * b.w;
        }
    }

    const float alpha = (MODE == 1) ? alphap[0] : 0.f;
#pragma unroll
    for (int i = 0; i < 4; ++i) {
        int vr = row0 + ty * 4 + i;
        if (vr >= N) continue;
        float dg = 1.f;
        if (MODE != 2) dg = fmaxf((float)(rp2[vr * 4 + 4] - rp2[vr * 4]), 1.f);
#pragma unroll
        for (int j = 0; j < 4; ++j) {
            int col = tx * 4 + j;
            if (MODE == 0) {
                OUT[(size_t)vr * 64 + col] = fmaxf(acc[i][j] / dg, 0.f);
            } else if (MODE == 1) {
                OUT[(size_t)vr * 64 + col] =
                    X[(size_t)vr * 64 + col] + alpha * (acc[i][j] / dg + bias[col]);
            } else {
                if (col < 32) OUT[(size_t)vr * 32 + col] = acc[i][j] + bias[col];
            }
        }
    }
}

extern "C" void kernel_launch(void* const* d_in, const int* in_sizes, int n_in,
                              void* d_out, int out_size, void* d_ws, size_t ws_size,
                              hipStream_t stream) {
    const float* x      = (const float*)d_in[0];
    const int*   ei     = (const int*)d_in[1];
    const int*   et     = (const int*)d_in[2];
    const float* ew     = (const float*)d_in[3];
    const float* W1     = (const float*)d_in[4];
    const float* W01    = (const float*)d_in[5];
    const float* alpha1 = (const float*)d_in[6];
    const float* projW1 = (const float*)d_in[7];
    const float* projb1 = (const float*)d_in[8];
    const float* W2     = (const float*)d_in[9];
    const float* W02    = (const float*)d_in[10];
    const float* alpha2 = (const float*)d_in[11];
    const float* projW2 = (const float*)d_in[12];
    const float* projb2 = (const float*)d_in[13];
    const float* outW   = (const float*)d_in[14];
    const float* outb   = (const float*)d_in[15];
    const int N = in_sizes[0] / 64;
    const int E = in_sizes[2];
    const int M = 4 * N;            // (dst, rel) segments
    const int NB = (N + 255) >> 8;  // 256-node dst buckets (NB <= 1024 for N <= 262144)

    // workspace (4-byte units):
    // bcnt[1024] | bofs[1032] | bcur[1024] | rp2[M+1 (+pad to even)] |
    // pw int2[E] | aggR[N*256] (recA int2[E] + recB int[E] aliased inside,
    // CSR-build only) | h[N*64] | g[N*64]
    int*   bcnt = (int*)d_ws;
    int*   bofs = bcnt + 1024;
    int*   bcur = bofs + 1032;
    int*   rp2  = bcur + 1024;
    int2*  pw   = (int2*)(rp2 + ((M + 2) & ~1));
    float* aggR = (float*)(pw + E);
    int2*  recA = (int2*)aggR;            // alias: dead once gather_rel runs
    int*   recB = (int*)(recA + E);
    float* hbuf = aggR + (size_t)N * 256;
    float* gbuf = hbuf + (size_t)N * 64;

    const int gatherBlocks = (N + 3) / 4;
    const int gemmBlocks = (N + 63) / 64;
    const int pBlocks = (E + PART_EPB - 1) / PART_EPB;

    // ---- CSR build (block-aggregated radix partition, once per call) ----
    hipMemsetAsync(bcnt, 0, 1024 * sizeof(int), stream);
    bucket_hist<<<pBlocks, 256, 0, stream>>>(ei, bcnt, E, NB);
    bucket_scan<<<1, 1024, 0, stream>>>(bcnt, bofs, bcur, NB, E);
    partition<<<pBlocks, 256, 0, stream>>>(ei, et, ew, bcur, recA, recB, E, NB);
    bucket_fill<<<NB, 256, 0, stream>>>(recA, recB, bofs, rp2, pw, N);

    // ---- layer 1 ----
    gather_rel<<<gatherBlocks, 256, 0, stream>>>(x, rp2, pw, aggR, N);
    node_gemm<0><<<gemmBlocks, 256, 0, stream>>>(x, aggR, W01, W1, nullptr, nullptr, rp2, hbuf, N);
    gather_plain<<<gatherBlocks, 256, 0, stream>>>(hbuf, rp2, pw, aggR, N);
    node_gemm<1><<<gemmBlocks, 256, 0, stream>>>(hbuf, aggR, projW1, nullptr, projb1, alpha1, rp2, gbuf, N);

    // ---- layer 2 ----
    gather_rel<<<gatherBlocks, 256, 0, stream>>>(gbuf, rp2, pw, aggR, N);
    node_gemm<0><<<gemmBlocks, 256, 0, stream>>>(gbuf, aggR, W02, W2, nullptr, nullptr, rp2, hbuf, N);
    gather_plain<<<gatherBlocks, 256, 0, stream>>>(hbuf, rp2, pw, aggR, N);
    node_gemm<1><<<gemmBlocks, 256, 0, stream>>>(hbuf, aggR, projW2, nullptr, projb2, alpha2, rp2, gbuf, N);

    // ---- head ----
    node_gemm<2><<<gemmBlocks, 256, 0, stream>>>(gbuf, nullptr, outW, nullptr, outb, nullptr, rp2, (float*)d_out, N);
}

// Round 3
// 457.272 us; speedup vs baseline: 1.4332x; 1.0875x over previous
//
#include <hip/hip_runtime.h>

// ---------------------------------------------------------------------------
// MR_GNN: 2x (RGCN + GroupEnhance) + linear head.
// R5 -> R6: partition/hist were latency-bound at 2.3% occupancy (only 62
// blocks: PART_EPB=16384). Shrink to PART_EPB=2048 -> 489 blocks, ~8x more
// resident waves to hide gather/atomic latency. Per-(block,bucket) runs drop
// to ~80B (write amp ~1.5-2x, still cheap); reserve atomics 96K total over
// 196 addresses -- uncontended. Everything else unchanged.
// ---------------------------------------------------------------------------

#define PART_EPB 2048  // edges per partition/hist block (256 thr x 8)

// ---- CSR build, pass A1: per-bucket edge counts (bucket = dst >> 8) ----
__global__ __launch_bounds__(256) void bucket_hist(const int* __restrict__ ei,
                                                   int* __restrict__ bcnt,
                                                   int E, int NB) {
    __shared__ int h[1024];
    for (int i = threadIdx.x; i < 1024; i += 256) h[i] = 0;
    __syncthreads();
    int base = blockIdx.x * PART_EPB;
#pragma unroll
    for (int k = 0; k < PART_EPB / 256; ++k) {
        int e = base + k * 256 + threadIdx.x;
        if (e < E) atomicAdd(&h[ei[E + e] >> 8], 1);
    }
    __syncthreads();
    for (int i = threadIdx.x; i < NB; i += 256)
        if (h[i]) atomicAdd(&bcnt[i], h[i]);
}

// ---- pass A-scan: exclusive scan of NB (<=1024) bucket counts ----
__global__ __launch_bounds__(1024) void bucket_scan(const int* __restrict__ bcnt,
                                                    int* __restrict__ bofs,
                                                    int* __restrict__ bcur,
                                                    int NB, int E) {
    __shared__ int lds[1024];
    int tid = threadIdx.x;
    int v = (tid < NB) ? bcnt[tid] : 0;
    lds[tid] = v;
    __syncthreads();
    int acc = v;
    for (int off = 1; off < 1024; off <<= 1) {
        int t = (tid >= off) ? lds[tid - off] : 0;
        __syncthreads();
        acc += t;
        lds[tid] = acc;
        __syncthreads();
    }
    int excl = acc - v;
    if (tid < NB) { bofs[tid] = excl; bcur[tid] = excl; }
    if (tid == 0) bofs[NB] = E;
}

// ---- pass A2: block-aggregated partition into bucket streams ----
// pass 1: LDS bucket histogram over this block's edges;
// reserve: one global atomicAdd per (block,bucket);
// pass 2: scatter into the reserved contiguous runs.
// recA[pos] = (src, w_bits); recB[pos] = dst*4 + rel
__global__ __launch_bounds__(256) void partition(const int* __restrict__ ei,
                                                 const int* __restrict__ et,
                                                 const float* __restrict__ ew,
                                                 int* __restrict__ gcur,
                                                 int2* __restrict__ recA,
                                                 int* __restrict__ recB,
                                                 int E, int NB) {
    __shared__ int hist[1024];
    __shared__ int base[1024];
    const int tid = threadIdx.x;
    const int blockBase = blockIdx.x * PART_EPB;
    for (int i = tid; i < 1024; i += 256) hist[i] = 0;
    __syncthreads();
#pragma unroll
    for (int k = 0; k < PART_EPB / 256; ++k) {
        int e = blockBase + k * 256 + tid;
        if (e < E) atomicAdd(&hist[ei[E + e] >> 8], 1);
    }
    __syncthreads();
    for (int i = tid; i < NB; i += 256) {
        int h = hist[i];
        base[i] = h ? atomicAdd(&gcur[i], h) : 0;
    }
    __syncthreads();
    for (int i = tid; i < 1024; i += 256) hist[i] = 0;  // reuse as run cursor
    __syncthreads();
#pragma unroll
    for (int k = 0; k < PART_EPB / 256; ++k) {
        int e = blockBase + k * 256 + tid;
        if (e >= E) continue;
        int dst = ei[E + e];
        int b = dst >> 8;
        int pos = base[b] + atomicAdd(&hist[b], 1);
        recA[pos] = make_int2(ei[e], __float_as_int(ew[e]));
        recB[pos] = dst * 4 + et[e];
    }
}

// ---- pass B: per-bucket (node,rel) hist + scan in LDS, write rp2 + pw ----
// One block per bucket of 256 nodes (1024 (node,rel) counters, 4/thread).
__global__ __launch_bounds__(256) void bucket_fill(
    const int2* __restrict__ recA, const int* __restrict__ recB,
    const int* __restrict__ bofs, int* __restrict__ rp2, int2* __restrict__ pw,
    int N) {
    __shared__ int cnt[1024];
    __shared__ int cur[1024];
    __shared__ int wsum[4];
    const int b = blockIdx.x;
    const int tid = threadIdx.x;
    const int beg = bofs[b], end = bofs[b + 1];
    const int rebase = b << 10;  // base index in (dst*4+rel) space
    for (int j = 0; j < 4; ++j) cnt[tid * 4 + j] = 0;
    __syncthreads();
    for (int i = beg + tid; i < end; i += 256)
        atomicAdd(&cnt[recB[i] - rebase], 1);
    __syncthreads();
    // exclusive scan of the 1024 counters: 4 consecutive per thread,
    // wave scan of thread sums + wave-sum fixup.
    int v[4];
    int s = 0;
#pragma unroll
    for (int j = 0; j < 4; ++j) { v[j] = cnt[tid * 4 + j]; s += v[j]; }
    int lane = tid & 63, wid = tid >> 6;
    int ws = s;
#pragma unroll
    for (int off = 1; off < 64; off <<= 1) {
        int t = __shfl_up(ws, off);
        if (lane >= off) ws += t;
    }
    if (lane == 63) wsum[wid] = ws;
    __syncthreads();
    int wb = 0;
    for (int w = 0; w < wid; ++w) wb += wsum[w];
    int run = beg + wb + ws - s;  // global CSR position of this thread's 1st counter
#pragma unroll
    for (int j = 0; j < 4; ++j) {
        int idx = rebase + tid * 4 + j;
        if (idx <= 4 * N) rp2[idx] = run;
        cur[tid * 4 + j] = run;  // global write cursor for this (node,rel)
        run += v[j];
    }
    __syncthreads();
    for (int i = beg + tid; i < end; i += 256) {
        int l = recB[i] - rebase;
        int p = atomicAdd(&cur[l], 1);
        pw[p] = recA[i];  // scatter confined to [beg,end): ~40KB, L2-resident
    }
}

__device__ __forceinline__ float4 quad_reduce(float4 a) {
#pragma unroll
    for (int off = 16; off < 64; off <<= 1) {
        a.x += __shfl_xor(a.x, off);
        a.y += __shfl_xor(a.y, off);
        a.z += __shfl_xor(a.z, off);
        a.w += __shfl_xor(a.w, off);
    }
    return a;
}

// one wave per node; lane = 16*q + m: quarter q handles edges beg+q+4k,
// m indexes a float4 of the 64-feature row. 4 relation segments in sequence.
__global__ __launch_bounds__(256) void gather_rel(
    const float* __restrict__ X, const int* __restrict__ rp2,
    const int2* __restrict__ pw, float* __restrict__ aggR, int N) {
    int node = blockIdx.x * 4 + (threadIdx.x >> 6);
    if (node >= N) return;
    int lane = threadIdx.x & 63;
    int q = lane >> 4, m = lane & 15;
#pragma unroll
    for (int r = 0; r < 4; ++r) {
        int beg = rp2[node * 4 + r], end = rp2[node * 4 + r + 1];
        float4 acc = make_float4(0.f, 0.f, 0.f, 0.f);
        int i = beg + q;
        for (; i + 4 < end; i += 8) {  // two independent gathers per iter
            int2 a = pw[i];
            int2 b = pw[i + 4];
            float4 xa = *reinterpret_cast<const float4*>(X + (size_t)a.x * 64 + m * 4);
            float4 xb = *reinterpret_cast<const float4*>(X + (size_t)b.x * 64 + m * 4);
            float wa = __int_as_float(a.y), wb = __int_as_float(b.y);
            acc.x += wa * xa.x; acc.y += wa * xa.y; acc.z += wa * xa.z; acc.w += wa * xa.w;
            acc.x += wb * xb.x; acc.y += wb * xb.y; acc.z += wb * xb.z; acc.w += wb * xb.w;
        }
        if (i < end) {
            int2 a = pw[i];
            float4 xa = *reinterpret_cast<const float4*>(X + (size_t)a.x * 64 + m * 4);
            float wa = __int_as_float(a.y);
            acc.x += wa * xa.x; acc.y += wa * xa.y; acc.z += wa * xa.z; acc.w += wa * xa.w;
        }
        acc = quad_reduce(acc);
        if (q == r)
            *reinterpret_cast<float4*>(aggR + (size_t)node * 256 + r * 64 + m * 4) = acc;
    }
}

__global__ __launch_bounds__(256) void gather_plain(
    const float* __restrict__ H, const int* __restrict__ rp2,
    const int2* __restrict__ pw, float* __restrict__ agg, int N) {
    int node = blockIdx.x * 4 + (threadIdx.x >> 6);
    if (node >= N) return;
    int lane = threadIdx.x & 63;
    int q = lane >> 4, m = lane & 15;
    int beg = rp2[node * 4], end = rp2[node * 4 + 4];
    float4 acc = make_float4(0.f, 0.f, 0.f, 0.f);
    int i = beg + q;
    for (; i + 4 < end; i += 8) {
        int2 a = pw[i];
        int2 b = pw[i + 4];
        float4 xa = *reinterpret_cast<const float4*>(H + (size_t)a.x * 64 + m * 4);
        float4 xb = *reinterpret_cast<const float4*>(H + (size_t)b.x * 64 + m * 4);
        float wa = __int_as_float(a.y), wb = __int_as_float(b.y);
        acc.x += wa * xa.x; acc.y += wa * xa.y; acc.z += wa * xa.z; acc.w += wa * xa.w;
        acc.x += wb * xb.x; acc.y += wb * xb.y; acc.z += wb * xb.z; acc.w += wb * xb.w;
    }
    if (i < end) {
        int2 a = pw[i];
        float4 xa = *reinterpret_cast<const float4*>(H + (size_t)a.x * 64 + m * 4);
        float wa = __int_as_float(a.y);
        acc.x += wa * xa.x; acc.y += wa * xa.y; acc.z += wa * xa.z; acc.w += wa * xa.w;
    }
    acc = quad_reduce(acc);
    if (q == 0)
        *reinterpret_cast<float4*>(agg + (size_t)node * 64 + m * 4) = acc;
}

// ---------------------------------------------------------------------------
// Node-side tiled GEMM (deg from rp2 row bounds).
// MODE 0 (rgcn):  OUT = relu((X@B0 + AGG@B1) / deg)        OUT: N x 64
// MODE 1 (group): OUT = X + alpha*((AGG@B0)/deg + bias)    OUT: N x 64
// MODE 2 (head):  OUT = X@B0 + bias                        OUT: N x 32
// ---------------------------------------------------------------------------
template <int MODE>
__global__ __launch_bounds__(256) void node_gemm(
    const float* __restrict__ X, const float* __restrict__ AGG,
    const float* __restrict__ B0, const float* __restrict__ B1,
    const float* __restrict__ bias, const float* __restrict__ alphap,
    const int* __restrict__ rp2, float* __restrict__ OUT, int N) {
    __shared__ float As[64][68];
    __shared__ float Bs[64][64];
    const int tid = threadIdx.x;
    const int tx = tid & 15, ty = tid >> 4;
    const int row0 = blockIdx.x * 64;
    float acc[4][4] = {};

    const int nchunks = (MODE == 0) ? 5 : 1;
    for (int c = 0; c < nchunks; ++c) {
        const float* A;
        int lda;
        const float* B;
        int ldb, bcols;
        if (MODE == 0) {
            if (c == 0) { A = X; lda = 64; B = B0; }
            else        { A = AGG + (c - 1) * 64; lda = 256; B = B1 + (size_t)(c - 1) * 64 * 64; }
            ldb = 64; bcols = 64;
        } else if (MODE == 1) {
            A = AGG; lda = 64; B = B0; ldb = 64; bcols = 64;
        } else {
            A = X; lda = 64; B = B0; ldb = 32; bcols = 32;
        }
        if (c) __syncthreads();
#pragma unroll
        for (int q = 0; q < 4; ++q) {
            int f = q * 256 + tid;
            int r = f >> 4;
            int c4 = (f & 15) << 2;
            float4 v = make_float4(0.f, 0.f, 0.f, 0.f);
            int vr = row0 + r;
            if (vr < N) v = *reinterpret_cast<const float4*>(A + (size_t)vr * lda + c4);
            *reinterpret_cast<float4*>(&As[r][c4]) = v;
            float4 bv = make_float4(0.f, 0.f, 0.f, 0.f);
            if (c4 < bcols) bv = *reinterpret_cast<const float4*>(B + (size_t)r * ldb + c4);
            *reinterpret_cast<float4*>(&Bs[r][c4]) = bv;
        }
        __syncthreads();
#pragma unroll 8
        for (int k = 0; k < 64; ++k) {
            float4 b = *reinterpret_cast<const float4*>(&Bs[k][tx * 4]);
            float a0 = As[ty * 4 + 0][k];
            float a1 = As[ty * 4 + 1][k];
            float a2 = As[ty * 4 + 2][k];
            float a3 = As[ty * 4 + 3][k];
            acc[0][0] += a0 * b.x; acc[0][1] += a0 * b.y; acc[0][2] += a0 * b.z; acc[0][3] += a0 * b.w;
            acc[1][0] += a1 * b.x; acc[1][1] += a1 * b.y; acc[1][2] += a1 * b.z; acc[1][3] += a1 * b.w;
            acc[2][0] += a2 * b.x; acc[2][1] += a2 * b.y; acc[2][2] += a2 * b.z; acc[2][3] += a2 * b.w;
            acc[3][0] += a3 * b.x; acc[3][1] += a3 * b.y; acc[3][2] += a3 * b.z; acc[3][3] += a3 * b.w;
        }
    }

    const float alpha = (MODE == 1) ? alphap[0] : 0.f;
#pragma unroll
    for (int i = 0; i < 4; ++i) {
        int vr = row0 + ty * 4 + i;
        if (vr >= N) continue;
        float dg = 1.f;
        if (MODE != 2) dg = fmaxf((float)(rp2[vr * 4 + 4] - rp2[vr * 4]), 1.f);
#pragma unroll
        for (int j = 0; j < 4; ++j) {
            int col = tx * 4 + j;
            if (MODE == 0) {
                OUT[(size_t)vr * 64 + col] = fmaxf(acc[i][j] / dg, 0.f);
            } else if (MODE == 1) {
                OUT[(size_t)vr * 64 + col] =
                    X[(size_t)vr * 64 + col] + alpha * (acc[i][j] / dg + bias[col]);
            } else {
                if (col < 32) OUT[(size_t)vr * 32 + col] = acc[i][j] + bias[col];
            }
        }
    }
}

extern "C" void kernel_launch(void* const* d_in, const int* in_sizes, int n_in,
                              void* d_out, int out_size, void* d_ws, size_t ws_size,
                              hipStream_t stream) {
    const float* x      = (const float*)d_in[0];
    const int*   ei     = (const int*)d_in[1];
    const int*   et     = (const int*)d_in[2];
    const float* ew     = (const float*)d_in[3];
    const float* W1     = (const float*)d_in[4];
    const float* W01    = (const float*)d_in[5];
    const float* alpha1 = (const float*)d_in[6];
    const float* projW1 = (const float*)d_in[7];
    const float* projb1 = (const float*)d_in[8];
    const float* W2     = (const float*)d_in[9];
    const float* W02    = (const float*)d_in[10];
    const float* alpha2 = (const float*)d_in[11];
    const float* projW2 = (const float*)d_in[12];
    const float* projb2 = (const float*)d_in[13];
    const float* outW   = (const float*)d_in[14];
    const float* outb   = (const float*)d_in[15];
    const int N = in_sizes[0] / 64;
    const int E = in_sizes[2];
    const int M = 4 * N;            // (dst, rel) segments
    const int NB = (N + 255) >> 8;  // 256-node dst buckets (NB <= 1024 for N <= 262144)

    // workspace (4-byte units):
    // bcnt[1024] | bofs[1032] | bcur[1024] | rp2[M+1 (+pad to even)] |
    // pw int2[E] | aggR[N*256] (recA int2[E] + recB int[E] aliased inside,
    // CSR-build only) | h[N*64] | g[N*64]
    int*   bcnt = (int*)d_ws;
    int*   bofs = bcnt + 1024;
    int*   bcur = bofs + 1032;
    int*   rp2  = bcur + 1024;
    int2*  pw   = (int2*)(rp2 + ((M + 2) & ~1));
    float* aggR = (float*)(pw + E);
    int2*  recA = (int2*)aggR;            // alias: dead once gather_rel runs
    int*   recB = (int*)(recA + E);
    float* hbuf = aggR + (size_t)N * 256;
    float* gbuf = hbuf + (size_t)N * 64;

    const int gatherBlocks = (N + 3) / 4;
    const int gemmBlocks = (N + 63) / 64;
    const int pBlocks = (E + PART_EPB - 1) / PART_EPB;

    // ---- CSR build (block-aggregated radix partition, once per call) ----
    hipMemsetAsync(bcnt, 0, 1024 * sizeof(int), stream);
    bucket_hist<<<pBlocks, 256, 0, stream>>>(ei, bcnt, E, NB);
    bucket_scan<<<1, 1024, 0, stream>>>(bcnt, bofs, bcur, NB, E);
    partition<<<pBlocks, 256, 0, stream>>>(ei, et, ew, bcur, recA, recB, E, NB);
    bucket_fill<<<NB, 256, 0, stream>>>(recA, recB, bofs, rp2, pw, N);

    // ---- layer 1 ----
    gather_rel<<<gatherBlocks, 256, 0, stream>>>(x, rp2, pw, aggR, N);
    node_gemm<0><<<gemmBlocks, 256, 0, stream>>>(x, aggR, W01, W1, nullptr, nullptr, rp2, hbuf, N);
    gather_plain<<<gatherBlocks, 256, 0, stream>>>(hbuf, rp2, pw, aggR, N);
    node_gemm<1><<<gemmBlocks, 256, 0, stream>>>(hbuf, aggR, projW1, nullptr, projb1, alpha1, rp2, gbuf, N);

    // ---- layer 2 ----
    gather_rel<<<gatherBlocks, 256, 0, stream>>>(gbuf, rp2, pw, aggR, N);
    node_gemm<0><<<gemmBlocks, 256, 0, stream>>>(gbuf, aggR, W02, W2, nullptr, nullptr, rp2, hbuf, N);
    gather_plain<<<gatherBlocks, 256, 0, stream>>>(hbuf, rp2, pw, aggR, N);
    node_gemm<1><<<gemmBlocks, 256, 0, stream>>>(hbuf, aggR, projW2, nullptr, projb2, alpha2, rp2, gbuf, N);

    // ---- head ----
    node_gemm<2><<<gemmBlocks, 256, 0, stream>>>(gbuf, nullptr, outW, nullptr, outb, nullptr, rp2, (float*)d_out, N);
}

// Round 4
// 441.438 us; speedup vs baseline: 1.4846x; 1.0359x over previous
//
#include <hip/hip_runtime.h>

// ---------------------------------------------------------------------------
// MR_GNN: 2x (RGCN + GroupEnhance) + linear head.
// R6 -> R7: gathers were the top cost (4 passes ~45% of total) at 3.65 TB/s
// (58% of achievable) with only ~2 loads in flight and gather_rel serializing
// 4 short (avg-5-edge) segment rounds per node. Unified-range gather:
// process the node's whole contiguous [s0,s4) edge range (avg 20 edges) in a
// 4/2/1-deep pipelined loop; relation determined by position vs segment
// bounds, accumulated via masked weights into 4 register accumulators; one
// unconditional store per lane in the epilogue. gather_plain = same kernel
// with REL=0 (4 independent accumulator chains). CSR build unchanged.
// ---------------------------------------------------------------------------

#define PART_EPB 2048  // edges per partition/hist block (256 thr x 8)

// ---- CSR build, pass A1: per-bucket edge counts (bucket = dst >> 8) ----
__global__ __launch_bounds__(256) void bucket_hist(const int* __restrict__ ei,
                                                   int* __restrict__ bcnt,
                                                   int E, int NB) {
    __shared__ int h[1024];
    for (int i = threadIdx.x; i < 1024; i += 256) h[i] = 0;
    __syncthreads();
    int base = blockIdx.x * PART_EPB;
#pragma unroll
    for (int k = 0; k < PART_EPB / 256; ++k) {
        int e = base + k * 256 + threadIdx.x;
        if (e < E) atomicAdd(&h[ei[E + e] >> 8], 1);
    }
    __syncthreads();
    for (int i = threadIdx.x; i < NB; i += 256)
        if (h[i]) atomicAdd(&bcnt[i], h[i]);
}

// ---- pass A-scan: exclusive scan of NB (<=1024) bucket counts ----
__global__ __launch_bounds__(1024) void bucket_scan(const int* __restrict__ bcnt,
                                                    int* __restrict__ bofs,
                                                    int* __restrict__ bcur,
                                                    int NB, int E) {
    __shared__ int lds[1024];
    int tid = threadIdx.x;
    int v = (tid < NB) ? bcnt[tid] : 0;
    lds[tid] = v;
    __syncthreads();
    int acc = v;
    for (int off = 1; off < 1024; off <<= 1) {
        int t = (tid >= off) ? lds[tid - off] : 0;
        __syncthreads();
        acc += t;
        lds[tid] = acc;
        __syncthreads();
    }
    int excl = acc - v;
    if (tid < NB) { bofs[tid] = excl; bcur[tid] = excl; }
    if (tid == 0) bofs[NB] = E;
}

// ---- pass A2: block-aggregated partition into bucket streams ----
__global__ __launch_bounds__(256) void partition(const int* __restrict__ ei,
                                                 const int* __restrict__ et,
                                                 const float* __restrict__ ew,
                                                 int* __restrict__ gcur,
                                                 int2* __restrict__ recA,
                                                 int* __restrict__ recB,
                                                 int E, int NB) {
    __shared__ int hist[1024];
    __shared__ int base[1024];
    const int tid = threadIdx.x;
    const int blockBase = blockIdx.x * PART_EPB;
    for (int i = tid; i < 1024; i += 256) hist[i] = 0;
    __syncthreads();
#pragma unroll
    for (int k = 0; k < PART_EPB / 256; ++k) {
        int e = blockBase + k * 256 + tid;
        if (e < E) atomicAdd(&hist[ei[E + e] >> 8], 1);
    }
    __syncthreads();
    for (int i = tid; i < NB; i += 256) {
        int h = hist[i];
        base[i] = h ? atomicAdd(&gcur[i], h) : 0;
    }
    __syncthreads();
    for (int i = tid; i < 1024; i += 256) hist[i] = 0;  // reuse as run cursor
    __syncthreads();
#pragma unroll
    for (int k = 0; k < PART_EPB / 256; ++k) {
        int e = blockBase + k * 256 + tid;
        if (e >= E) continue;
        int dst = ei[E + e];
        int b = dst >> 8;
        int pos = base[b] + atomicAdd(&hist[b], 1);
        recA[pos] = make_int2(ei[e], __float_as_int(ew[e]));
        recB[pos] = dst * 4 + et[e];
    }
}

// ---- pass B: per-bucket (node,rel) hist + scan in LDS, write rp2 + pw ----
__global__ __launch_bounds__(256) void bucket_fill(
    const int2* __restrict__ recA, const int* __restrict__ recB,
    const int* __restrict__ bofs, int* __restrict__ rp2, int2* __restrict__ pw,
    int N) {
    __shared__ int cnt[1024];
    __shared__ int cur[1024];
    __shared__ int wsum[4];
    const int b = blockIdx.x;
    const int tid = threadIdx.x;
    const int beg = bofs[b], end = bofs[b + 1];
    const int rebase = b << 10;  // base index in (dst*4+rel) space
    for (int j = 0; j < 4; ++j) cnt[tid * 4 + j] = 0;
    __syncthreads();
    for (int i = beg + tid; i < end; i += 256)
        atomicAdd(&cnt[recB[i] - rebase], 1);
    __syncthreads();
    int v[4];
    int s = 0;
#pragma unroll
    for (int j = 0; j < 4; ++j) { v[j] = cnt[tid * 4 + j]; s += v[j]; }
    int lane = tid & 63, wid = tid >> 6;
    int ws = s;
#pragma unroll
    for (int off = 1; off < 64; off <<= 1) {
        int t = __shfl_up(ws, off);
        if (lane >= off) ws += t;
    }
    if (lane == 63) wsum[wid] = ws;
    __syncthreads();
    int wb = 0;
    for (int w = 0; w < wid; ++w) wb += wsum[w];
    int run = beg + wb + ws - s;
#pragma unroll
    for (int j = 0; j < 4; ++j) {
        int idx = rebase + tid * 4 + j;
        if (idx <= 4 * N) rp2[idx] = run;
        cur[tid * 4 + j] = run;
        run += v[j];
    }
    __syncthreads();
    for (int i = beg + tid; i < end; i += 256) {
        int l = recB[i] - rebase;
        int p = atomicAdd(&cur[l], 1);
        pw[p] = recA[i];
    }
}

__device__ __forceinline__ float4 quad_reduce(float4 a) {
#pragma unroll
    for (int off = 16; off < 64; off <<= 1) {
        a.x += __shfl_xor(a.x, off);
        a.y += __shfl_xor(a.y, off);
        a.z += __shfl_xor(a.z, off);
        a.w += __shfl_xor(a.w, off);
    }
    return a;
}

__device__ __forceinline__ void fma4(float4& a, float w, const float4& x) {
    a.x += w * x.x; a.y += w * x.y; a.z += w * x.z; a.w += w * x.w;
}

// ---------------------------------------------------------------------------
// Unified-range gather. One wave per node; lane = 16*q + m: quarter q handles
// edges s0+q+4k of the node's FULL contiguous edge range [s0,s4); m indexes a
// float4 of the 64-feature row. 4/2/1-deep load pipelining.
// REL=1: per-relation accumulators selected by edge position vs segment
//        bounds (masked weights); epilogue stores 4 relation rows (one per
//        quarter) to out[node*256 + q*64].    out: N x 256
// REL=0: 4 independent accumulator chains, summed; quarter 0 stores
//        out[node*64].                         out: N x 64
// ---------------------------------------------------------------------------
template <int REL>
__global__ __launch_bounds__(256) void gather_k(
    const float* __restrict__ X, const int* __restrict__ rp2,
    const int2* __restrict__ pw, float* __restrict__ out, int N) {
    int node = blockIdx.x * 4 + (threadIdx.x >> 6);
    if (node >= N) return;
    int lane = threadIdx.x & 63;
    int q = lane >> 4, m = lane & 15;
    const int4 sv = *reinterpret_cast<const int4*>(rp2 + node * 4);
    const int s0 = sv.x, s1 = sv.y, s2 = sv.z, s3 = sv.w;
    const int s4 = rp2[node * 4 + 4];
    float4 A0 = make_float4(0.f, 0.f, 0.f, 0.f);
    float4 A1 = make_float4(0.f, 0.f, 0.f, 0.f);
    float4 A2 = make_float4(0.f, 0.f, 0.f, 0.f);
    float4 A3 = make_float4(0.f, 0.f, 0.f, 0.f);

    auto accum = [&](int idx, int slot, int2 e, const float4& xv) {
        float w = __int_as_float(e.y);
        if (REL) {
            // relation of edge idx from its position in the segment chain
            fma4(A0, (idx < s1) ? w : 0.f, xv);
            fma4(A1, (idx >= s1 && idx < s2) ? w : 0.f, xv);
            fma4(A2, (idx >= s2 && idx < s3) ? w : 0.f, xv);
            fma4(A3, (idx >= s3) ? w : 0.f, xv);
        } else {
            // independent chains for ILP
            if (slot == 0) fma4(A0, w, xv);
            else if (slot == 1) fma4(A1, w, xv);
            else if (slot == 2) fma4(A2, w, xv);
            else fma4(A3, w, xv);
        }
    };

    int i = s0 + q;
    for (; i + 12 < s4; i += 16) {  // 4 gathers in flight
        int2 e0 = pw[i];
        int2 e1 = pw[i + 4];
        int2 e2 = pw[i + 8];
        int2 e3 = pw[i + 12];
        float4 x0 = *reinterpret_cast<const float4*>(X + (size_t)e0.x * 64 + m * 4);
        float4 x1 = *reinterpret_cast<const float4*>(X + (size_t)e1.x * 64 + m * 4);
        float4 x2 = *reinterpret_cast<const float4*>(X + (size_t)e2.x * 64 + m * 4);
        float4 x3 = *reinterpret_cast<const float4*>(X + (size_t)e3.x * 64 + m * 4);
        accum(i, 0, e0, x0);
        accum(i + 4, 1, e1, x1);
        accum(i + 8, 2, e2, x2);
        accum(i + 12, 3, e3, x3);
    }
    for (; i + 4 < s4; i += 8) {  // 2 in flight
        int2 e0 = pw[i];
        int2 e1 = pw[i + 4];
        float4 x0 = *reinterpret_cast<const float4*>(X + (size_t)e0.x * 64 + m * 4);
        float4 x1 = *reinterpret_cast<const float4*>(X + (size_t)e1.x * 64 + m * 4);
        accum(i, 0, e0, x0);
        accum(i + 4, 1, e1, x1);
    }
    if (i < s4) {
        int2 e0 = pw[i];
        float4 x0 = *reinterpret_cast<const float4*>(X + (size_t)e0.x * 64 + m * 4);
        accum(i, 0, e0, x0);
    }

    if (REL) {
        A0 = quad_reduce(A0);
        A1 = quad_reduce(A1);
        A2 = quad_reduce(A2);
        A3 = quad_reduce(A3);
        float4 o = (q == 0) ? A0 : (q == 1) ? A1 : (q == 2) ? A2 : A3;
        *reinterpret_cast<float4*>(out + (size_t)node * 256 + q * 64 + m * 4) = o;
    } else {
        A0.x += A1.x + A2.x + A3.x;
        A0.y += A1.y + A2.y + A3.y;
        A0.z += A1.z + A2.z + A3.z;
        A0.w += A1.w + A2.w + A3.w;
        A0 = quad_reduce(A0);
        if (q == 0)
            *reinterpret_cast<float4*>(out + (size_t)node * 64 + m * 4) = A0;
    }
}

// ---------------------------------------------------------------------------
// Node-side tiled GEMM (deg from rp2 row bounds).
// MODE 0 (rgcn):  OUT = relu((X@B0 + AGG@B1) / deg)        OUT: N x 64
// MODE 1 (group): OUT = X + alpha*((AGG@B0)/deg + bias)    OUT: N x 64
// MODE 2 (head):  OUT = X@B0 + bias                        OUT: N x 32
// ---------------------------------------------------------------------------
template <int MODE>
__global__ __launch_bounds__(256) void node_gemm(
    const float* __restrict__ X, const float* __restrict__ AGG,
    const float* __restrict__ B0, const float* __restrict__ B1,
    const float* __restrict__ bias, const float* __restrict__ alphap,
    const int* __restrict__ rp2, float* __restrict__ OUT, int N) {
    __shared__ float As[64][68];
    __shared__ float Bs[64][64];
    const int tid = threadIdx.x;
    const int tx = tid & 15, ty = tid >> 4;
    const int row0 = blockIdx.x * 64;
    float acc[4][4] = {};

    const int nchunks = (MODE == 0) ? 5 : 1;
    for (int c = 0; c < nchunks; ++c) {
        const float* A;
        int lda;
        const float* B;
        int ldb, bcols;
        if (MODE == 0) {
            if (c == 0) { A = X; lda = 64; B = B0; }
            else        { A = AGG + (c - 1) * 64; lda = 256; B = B1 + (size_t)(c - 1) * 64 * 64; }
            ldb = 64; bcols = 64;
        } else if (MODE == 1) {
            A = AGG; lda = 64; B = B0; ldb = 64; bcols = 64;
        } else {
            A = X; lda = 64; B = B0; ldb = 32; bcols = 32;
        }
        if (c) __syncthreads();
#pragma unroll
        for (int q = 0; q < 4; ++q) {
            int f = q * 256 + tid;
            int r = f >> 4;
            int c4 = (f & 15) << 2;
            float4 v = make_float4(0.f, 0.f, 0.f, 0.f);
            int vr = row0 + r;
            if (vr < N) v = *reinterpret_cast<const float4*>(A + (size_t)vr * lda + c4);
            *reinterpret_cast<float4*>(&As[r][c4]) = v;
            float4 bv = make_float4(0.f, 0.f, 0.f, 0.f);
            if (c4 < bcols) bv = *reinterpret_cast<const float4*>(B + (size_t)r * ldb + c4);
            *reinterpret_cast<float4*>(&Bs[r][c4]) = bv;
        }
        __syncthreads();
#pragma unroll 8
        for (int k = 0; k < 64; ++k) {
            float4 b = *reinterpret_cast<const float4*>(&Bs[k][tx * 4]);
            float a0 = As[ty * 4 + 0][k];
            float a1 = As[ty * 4 + 1][k];
            float a2 = As[ty * 4 + 2][k];
            float a3 = As[ty * 4 + 3][k];
            acc[0][0] += a0 * b.x; acc[0][1] += a0 * b.y; acc[0][2] += a0 * b.z; acc[0][3] += a0 * b.w;
            acc[1][0] += a1 * b.x; acc[1][1] += a1 * b.y; acc[1][2] += a1 * b.z; acc[1][3] += a1 * b.w;
            acc[2][0] += a2 * b.x; acc[2][1] += a2 * b.y; acc[2][2] += a2 * b.z; acc[2][3] += a2 * b.w;
            acc[3][0] += a3 * b.x; acc[3][1] += a3 * b.y; acc[3][2] += a3 * b.z; acc[3][3] += a3 * b.w;
        }
    }

    const float alpha = (MODE == 1) ? alphap[0] : 0.f;
#pragma unroll
    for (int i = 0; i < 4; ++i) {
        int vr = row0 + ty * 4 + i;
        if (vr >= N) continue;
        float dg = 1.f;
        if (MODE != 2) dg = fmaxf((float)(rp2[vr * 4 + 4] - rp2[vr * 4]), 1.f);
#pragma unroll
        for (int j = 0; j < 4; ++j) {
            int col = tx * 4 + j;
            if (MODE == 0) {
                OUT[(size_t)vr * 64 + col] = fmaxf(acc[i][j] / dg, 0.f);
            } else if (MODE == 1) {
                OUT[(size_t)vr * 64 + col] =
                    X[(size_t)vr * 64 + col] + alpha * (acc[i][j] / dg + bias[col]);
            } else {
                if (col < 32) OUT[(size_t)vr * 32 + col] = acc[i][j] + bias[col];
            }
        }
    }
}

extern "C" void kernel_launch(void* const* d_in, const int* in_sizes, int n_in,
                              void* d_out, int out_size, void* d_ws, size_t ws_size,
                              hipStream_t stream) {
    const float* x      = (const float*)d_in[0];
    const int*   ei     = (const int*)d_in[1];
    const int*   et     = (const int*)d_in[2];
    const float* ew     = (const float*)d_in[3];
    const float* W1     = (const float*)d_in[4];
    const float* W01    = (const float*)d_in[5];
    const float* alpha1 = (const float*)d_in[6];
    const float* projW1 = (const float*)d_in[7];
    const float* projb1 = (const float*)d_in[8];
    const float* W2     = (const float*)d_in[9];
    const float* W02    = (const float*)d_in[10];
    const float* alpha2 = (const float*)d_in[11];
    const float* projW2 = (const float*)d_in[12];
    const float* projb2 = (const float*)d_in[13];
    const float* outW   = (const float*)d_in[14];
    const float* outb   = (const float*)d_in[15];
    const int N = in_sizes[0] / 64;
    const int E = in_sizes[2];
    const int M = 4 * N;            // (dst, rel) segments
    const int NB = (N + 255) >> 8;  // 256-node dst buckets

    // workspace (4-byte units):
    // bcnt[1024] | bofs[1032] | bcur[1024] | rp2[M+1 (+pad to even)] |
    // pw int2[E] | aggR[N*256] (recA int2[E] + recB int[E] aliased inside,
    // CSR-build only) | h[N*64] | g[N*64]
    int*   bcnt = (int*)d_ws;
    int*   bofs = bcnt + 1024;
    int*   bcur = bofs + 1032;
    int*   rp2  = bcur + 1024;
    int2*  pw   = (int2*)(rp2 + ((M + 2) & ~1));
    float* aggR = (float*)(pw + E);
    int2*  recA = (int2*)aggR;            // alias: dead once gather runs
    int*   recB = (int*)(recA + E);
    float* hbuf = aggR + (size_t)N * 256;
    float* gbuf = hbuf + (size_t)N * 64;

    const int gatherBlocks = (N + 3) / 4;
    const int gemmBlocks = (N + 63) / 64;
    const int pBlocks = (E + PART_EPB - 1) / PART_EPB;

    // ---- CSR build (block-aggregated radix partition, once per call) ----
    hipMemsetAsync(bcnt, 0, 1024 * sizeof(int), stream);
    bucket_hist<<<pBlocks, 256, 0, stream>>>(ei, bcnt, E, NB);
    bucket_scan<<<1, 1024, 0, stream>>>(bcnt, bofs, bcur, NB, E);
    partition<<<pBlocks, 256, 0, stream>>>(ei, et, ew, bcur, recA, recB, E, NB);
    bucket_fill<<<NB, 256, 0, stream>>>(recA, recB, bofs, rp2, pw, N);

    // ---- layer 1 ----
    gather_k<1><<<gatherBlocks, 256, 0, stream>>>(x, rp2, pw, aggR, N);
    node_gemm<0><<<gemmBlocks, 256, 0, stream>>>(x, aggR, W01, W1, nullptr, nullptr, rp2, hbuf, N);
    gather_k<0><<<gatherBlocks, 256, 0, stream>>>(hbuf, rp2, pw, aggR, N);
    node_gemm<1><<<gemmBlocks, 256, 0, stream>>>(hbuf, aggR, projW1, nullptr, projb1, alpha1, rp2, gbuf, N);

    // ---- layer 2 ----
    gather_k<1><<<gatherBlocks, 256, 0, stream>>>(gbuf, rp2, pw, aggR, N);
    node_gemm<0><<<gemmBlocks, 256, 0, stream>>>(gbuf, aggR, W02, W2, nullptr, nullptr, rp2, hbuf, N);
    gather_k<0><<<gatherBlocks, 256, 0, stream>>>(hbuf, rp2, pw, aggR, N);
    node_gemm<1><<<gemmBlocks, 256, 0, stream>>>(hbuf, aggR, projW2, nullptr, projb2, alpha2, rp2, gbuf, N);

    // ---- head ----
    node_gemm<2><<<gemmBlocks, 256, 0, stream>>>(gbuf, nullptr, outW, nullptr, outb, nullptr, rp2, (float*)d_out, N);
}